// Round 3
// baseline (331.678 us; speedup 1.0000x reference)
//
#include <hip/hip_runtime.h>
#include <hip/hip_bf16.h>

// Restormer-style channel attention (MDTA). b=4, c=192, h=w=128 (n=16384),
// heads=4, ch=48. I/O dtype detected at runtime (fp32 vs bf16) — the
// reference file is float32 but the harness label hints bf16; a device-side
// detector samples x and every kernel branches uniformly.
//
// Pipeline (ws peak ~50.7 MB):
//   convert weights -> canonical bf16 in ws
//   Q: conv1x1 MFMA (Y -> d_out scratch, bf16) ; dwconv3x3 -> bufA, ssq += z^2
//   K: conv1x1 -> d_out ; dwconv -> bufB, ssk
//   S[bh][i][j] = Q_i . K_j      (MFMA over n, 16 chunks, global atomics)
//   softmax with L2 norms + temperature folded (normalize commutes with dot)
//   V: conv1x1 -> d_out ; dwconv -> bufA (Q dead)
//   out = attn . V               (K=48 skinny GEMM, store in detected dtype)

typedef __attribute__((ext_vector_type(8))) short short8;
typedef __attribute__((ext_vector_type(4))) float f32x4;

#define NB 4
#define NC 192
#define NN 16384
#define CH 48
#define NWELEM 115780   // 3*36864 + 3*1728 + 4 canonical weight elems

__device__ inline unsigned short f2bf(float f) {
  union { float f; unsigned int u; } c; c.f = f;
  unsigned int r = c.u + 0x7FFF + ((c.u >> 16) & 1);   // RNE
  return (unsigned short)(r >> 16);
}
__device__ inline float bf2f(unsigned short u) {
  union { unsigned int u; float f; } c; c.u = ((unsigned int)u) << 16;
  return c.f;
}

// Detect whether x is fp32 (true) or bf16 (false). Wave-uniform verdict.
// Even-index shorts of an fp32 buffer are low mantissa bits -> random bf16
// exponents (~70% extreme). Real bf16 data N(0,~1) never has extreme exps.
__device__ inline bool detect_f32(const unsigned short* x) {
  int l = threadIdx.x & 63;
  unsigned short u = x[2 * (l * 997 + 1)];
  int e = (u >> 7) & 0xFF;
  bool extreme = (e < 90) || (e > 165);
  return __popcll(__ballot(extreme)) >= 8;
}

// ------------------------------------------------------------ weight convert
__global__ __launch_bounds__(256) void k_convert(const unsigned short* __restrict__ x,
                                                 const void* wq, const void* wk, const void* wv,
                                                 const void* wqd, const void* wkd, const void* wvd,
                                                 const void* temp,
                                                 unsigned short* __restrict__ canon) {
  bool f32 = detect_f32(x);
  int i = blockIdx.x * 256 + threadIdx.x;
  if (i >= NWELEM) return;
  const void* src; int off;
  if (i < 36864)       { src = wq;  off = i; }
  else if (i < 73728)  { src = wk;  off = i - 36864; }
  else if (i < 110592) { src = wv;  off = i - 73728; }
  else if (i < 112320) { src = wqd; off = i - 110592; }
  else if (i < 114048) { src = wkd; off = i - 112320; }
  else if (i < 115776) { src = wvd; off = i - 114048; }
  else                 { src = temp; off = i - 115776; }
  canon[i] = f32 ? f2bf(((const float*)src)[off])
                 : ((const unsigned short*)src)[off];
}

// ------------------------------------------------------------ conv1x1 (MFMA)
// Y[b][d][p] = sum_c W[d][c] * X[b][c][p]; A-frags from global canon W,
// X staged transposed into LDS [p][c] (dtype-adaptive), bf16.
#define LDP 200   // padded LDS row stride (bf16 elems)
__global__ __launch_bounds__(256) void k_conv1x1(const unsigned short* __restrict__ Wc,
                                                 const unsigned short* __restrict__ X,
                                                 __hip_bfloat16* __restrict__ Y) {
  __shared__ __align__(16) unsigned short Xs[128 * LDP];   // 51.2 KB
  bool f32 = detect_f32(X);
  int b = blockIdx.z;
  int d0 = blockIdx.y * 64;
  int p0 = blockIdx.x * 128;
  int tid = threadIdx.x;
  if (f32) {
    const float* Xf = (const float*)X;
    for (int it = 0; it < 24; ++it) {
      int idx = it * 256 + tid;       // 0..6143
      int c = idx >> 5;               // 0..191
      int p4 = idx & 31;              // float4 chunk along p
      float4 v = *(const float4*)(Xf + ((size_t)b * NC + c) * NN + p0 + p4 * 4);
      Xs[(p4 * 4 + 0) * LDP + c] = f2bf(v.x);
      Xs[(p4 * 4 + 1) * LDP + c] = f2bf(v.y);
      Xs[(p4 * 4 + 2) * LDP + c] = f2bf(v.z);
      Xs[(p4 * 4 + 3) * LDP + c] = f2bf(v.w);
    }
  } else {
    for (int it = 0; it < 12; ++it) {
      int idx = it * 256 + tid;       // 0..3071
      int c = idx >> 4;               // 0..191
      int p8 = idx & 15;              // short8 chunk along p
      short8 v = *(const short8*)(X + ((size_t)b * NC + c) * NN + p0 + p8 * 8);
#pragma unroll
      for (int j = 0; j < 8; ++j)
        Xs[(p8 * 8 + j) * LDP + c] = (unsigned short)v[j];
    }
  }
  __syncthreads();
  int lane = tid & 63, w = tid >> 6;
  int wm = w & 1, wn = w >> 1;        // wave -> 32d x 64p quadrant
  int lrow = lane & 15, lq = lane >> 4;
  f32x4 acc[2][4];
  for (int mt = 0; mt < 2; ++mt)
    for (int nt = 0; nt < 4; ++nt) acc[mt][nt] = (f32x4){0.f, 0.f, 0.f, 0.f};
  for (int ks = 0; ks < 6; ++ks) {    // K = 192 = 6*32
    int k = ks * 32 + lq * 8;
    short8 a[2], bf[4];
    for (int mt = 0; mt < 2; ++mt)
      a[mt] = *(const short8*)(Wc + (size_t)(d0 + wm * 32 + mt * 16 + lrow) * NC + k);
    for (int nt = 0; nt < 4; ++nt)
      bf[nt] = *(const short8*)(&Xs[(wn * 64 + nt * 16 + lrow) * LDP + k]);
    for (int mt = 0; mt < 2; ++mt)
      for (int nt = 0; nt < 4; ++nt)
        acc[mt][nt] = __builtin_amdgcn_mfma_f32_16x16x32_bf16(a[mt], bf[nt], acc[mt][nt], 0, 0, 0);
  }
  // C/D layout: col = lane&15 (n=p), row = quad*4 + reg (m=d)
  for (int mt = 0; mt < 2; ++mt)
    for (int nt = 0; nt < 4; ++nt)
      for (int r = 0; r < 4; ++r) {
        int d = d0 + wm * 32 + mt * 16 + lq * 4 + r;
        int p = p0 + wn * 64 + nt * 16 + lrow;
        Y[((size_t)b * NC + d) * NN + p] = __float2bfloat16(acc[mt][nt][r]);
      }
}

// ------------------------------------------------------------ dwconv3x3 (+ sumsq)
__global__ __launch_bounds__(256) void k_dwconv(const __hip_bfloat16* __restrict__ Y,
                                                const unsigned short* __restrict__ Wdc,
                                                __hip_bfloat16* __restrict__ P,
                                                float* __restrict__ ss) {
  __shared__ float Ys[34][130];
  __shared__ float red[4];
  int b = blockIdx.z, c = blockIdx.y, r0 = blockIdx.x * 32;
  int tid = threadIdx.x;
  const __hip_bfloat16* base = Y + ((size_t)b * NC + c) * NN;
  for (int it = 0; it < 17; ++it) {   // 34 rows x 128 cols
    int idx = it * 256 + tid;
    int r = idx >> 7, col = idx & 127;
    int gr = r0 - 1 + r;
    float v = (gr >= 0 && gr < 128) ? __bfloat162float(base[gr * 128 + col]) : 0.f;
    Ys[r][col + 1] = v;
  }
  if (tid < 34) { Ys[tid][0] = 0.f; Ys[tid][129] = 0.f; }
  float wk9[9];
  for (int i = 0; i < 9; ++i) wk9[i] = bf2f(Wdc[c * 9 + i]);
  __syncthreads();
  float ssacc = 0.f;
  for (int it = 0; it < 16; ++it) {   // 32 rows x 128 cols
    int idx = it * 256 + tid;
    int r = idx >> 7, col = idx & 127;
    float z = 0.f;
    for (int dy = 0; dy < 3; ++dy)
      for (int dx = 0; dx < 3; ++dx)
        z += wk9[dy * 3 + dx] * Ys[r + dy][col + dx];
    P[((size_t)b * NC + c) * NN + (r0 + r) * 128 + col] = __float2bfloat16(z);
    ssacc += z * z;
  }
  if (ss) {
    for (int off = 32; off; off >>= 1) ssacc += __shfl_down(ssacc, off);
    if ((tid & 63) == 0) red[tid >> 6] = ssacc;
    __syncthreads();
    if (tid == 0) atomicAdd(&ss[b * NC + c], red[0] + red[1] + red[2] + red[3]);
  }
}

// ------------------------------------------------------------ S = Q.K^T
__global__ __launch_bounds__(256) void k_attn(const unsigned short* __restrict__ Qp,
                                              const unsigned short* __restrict__ Kp,
                                              float* __restrict__ S) {
  __shared__ float Sred[CH * CH];
  int bh = blockIdx.y, chunk = blockIdx.x;
  int b = bh >> 2, h = bh & 3;
  int tid = threadIdx.x, lane = tid & 63, w = tid >> 6;
  int lrow = lane & 15, lq = lane >> 4;
  const unsigned short* Qb = Qp + ((size_t)b * NC + h * CH) * NN;
  const unsigned short* Kb = Kp + ((size_t)b * NC + h * CH) * NN;
  int nbase = chunk * 1024 + w * 256;
  f32x4 acc[3][3];
  for (int i = 0; i < 3; ++i)
    for (int j = 0; j < 3; ++j) acc[i][j] = (f32x4){0.f, 0.f, 0.f, 0.f};
  for (int ks = 0; ks < 8; ++ks) {
    int n = nbase + ks * 32 + lq * 8;
    short8 a[3], bb[3];
    for (int t = 0; t < 3; ++t) a[t]  = *(const short8*)(Qb + (size_t)(t * 16 + lrow) * NN + n);
    for (int t = 0; t < 3; ++t) bb[t] = *(const short8*)(Kb + (size_t)(t * 16 + lrow) * NN + n);
    for (int ti = 0; ti < 3; ++ti)
      for (int tj = 0; tj < 3; ++tj)
        acc[ti][tj] = __builtin_amdgcn_mfma_f32_16x16x32_bf16(a[ti], bb[tj], acc[ti][tj], 0, 0, 0);
  }
  for (int i = tid; i < CH * CH; i += 256) Sred[i] = 0.f;
  __syncthreads();
  for (int ti = 0; ti < 3; ++ti)
    for (int tj = 0; tj < 3; ++tj)
      for (int r = 0; r < 4; ++r) {
        int row = ti * 16 + lq * 4 + r, col = tj * 16 + lrow;
        atomicAdd(&Sred[row * CH + col], acc[ti][tj][r]);
      }
  __syncthreads();
  float* Sg = S + bh * (CH * CH);
  for (int i = tid; i < CH * CH; i += 256) atomicAdd(&Sg[i], Sred[i]);
}

// ------------------------------------------------------------ softmax (+ norms)
__global__ void k_softmax(const float* __restrict__ S, const float* __restrict__ ssq,
                          const float* __restrict__ ssk, const unsigned short* __restrict__ tempc,
                          float* __restrict__ AT) {   // AT[bh][j][i]
  int bh = blockIdx.x, b = bh >> 2, h = bh & 3;
  int i = threadIdx.x;
  if (i >= CH) return;
  float t = bf2f(tempc[h]);
  float rq = 1.f / fmaxf(sqrtf(ssq[b * NC + h * CH + i]), 1e-12f);
  const float* Srow = S + bh * (CH * CH) + i * CH;
  float l[CH];
  float m = -1e30f;
  for (int j = 0; j < CH; ++j) {
    float rk = 1.f / fmaxf(sqrtf(ssk[b * NC + h * CH + j]), 1e-12f);
    l[j] = Srow[j] * rq * rk * t;
    m = fmaxf(m, l[j]);
  }
  float s = 0.f;
  for (int j = 0; j < CH; ++j) { l[j] = __expf(l[j] - m); s += l[j]; }
  float inv = 1.f / s;
  for (int j = 0; j < CH; ++j) AT[bh * (CH * CH) + j * CH + i] = l[j] * inv;
}

// ------------------------------------------------------------ out = attn . V
__global__ __launch_bounds__(256) void k_out(const float* __restrict__ AT,
                                             const __hip_bfloat16* __restrict__ Vp,
                                             void* __restrict__ Out,
                                             const unsigned short* __restrict__ x) {
  bool f32 = detect_f32(x);
  int bh = blockIdx.y, b = bh >> 2, h = bh & 3;
  int p0 = blockIdx.x * 512 + threadIdx.x;   // this thread: p0 and p0+256
  const float* A = AT + bh * (CH * CH);      // [j][i], block-uniform
  const __hip_bfloat16* Vb = Vp + ((size_t)b * NC + h * CH) * NN;
  float acc1[CH], acc2[CH];
  for (int i = 0; i < CH; ++i) { acc1[i] = 0.f; acc2[i] = 0.f; }
  for (int j = 0; j < CH; ++j) {
    float v1 = __bfloat162float(Vb[(size_t)j * NN + p0]);
    float v2 = __bfloat162float(Vb[(size_t)j * NN + p0 + 256]);
    const float* Aj = A + j * CH;
    for (int i = 0; i < CH; ++i) {
      float a = Aj[i];
      acc1[i] += a * v1;
      acc2[i] += a * v2;
    }
  }
  size_t obase = ((size_t)b * NC + h * CH) * NN;
  if (f32) {
    float* Of = (float*)Out;
    for (int i = 0; i < CH; ++i) {
      Of[obase + (size_t)i * NN + p0]       = acc1[i];
      Of[obase + (size_t)i * NN + p0 + 256] = acc2[i];
    }
  } else {
    __hip_bfloat16* Ob = (__hip_bfloat16*)Out;
    for (int i = 0; i < CH; ++i) {
      Ob[obase + (size_t)i * NN + p0]       = __float2bfloat16(acc1[i]);
      Ob[obase + (size_t)i * NN + p0 + 256] = __float2bfloat16(acc2[i]);
    }
  }
}

// ------------------------------------------------------------ launch
extern "C" void kernel_launch(void* const* d_in, const int* in_sizes, int n_in,
                              void* d_out, int out_size, void* d_ws, size_t ws_size,
                              hipStream_t stream) {
  const unsigned short* x = (const unsigned short*)d_in[0];

  const size_t TEN = (size_t)NB * NC * NN;   // 12,582,912 elems
  unsigned short* bufA = (unsigned short*)d_ws;   // Q', later V'
  unsigned short* bufB = bufA + TEN;              // K'
  float* ssq = (float*)(bufB + TEN);
  float* ssk = ssq + NB * NC;
  float* S   = ssk + NB * NC;
  float* AT  = S + 16 * CH * CH;
  unsigned short* canon = (unsigned short*)(AT + 16 * CH * CH);
  // ws total ~= 50.7 MB
  const unsigned short* Wq  = canon;
  const unsigned short* Wk  = canon + 36864;
  const unsigned short* Wv  = canon + 73728;
  const unsigned short* Wqd = canon + 110592;
  const unsigned short* Wkd = canon + 112320;
  const unsigned short* Wvd = canon + 114048;
  const unsigned short* Tmp = canon + 115776;

  hipMemsetAsync(ssq, 0, (2 * NB * NC + 16 * CH * CH) * sizeof(float), stream);
  k_convert<<<(NWELEM + 255) / 256, 256, 0, stream>>>(
      x, d_in[1], d_in[3], d_in[5], d_in[2], d_in[4], d_in[6], d_in[7], canon);

  __hip_bfloat16* Ysc = (__hip_bfloat16*)d_out;   // Y scratch (bf16, fits either out dtype)

  // Q
  k_conv1x1<<<dim3(NN / 128, NC / 64, NB), 256, 0, stream>>>(Wq, x, Ysc);
  k_dwconv<<<dim3(4, NC, NB), 256, 0, stream>>>(Ysc, Wqd, (__hip_bfloat16*)bufA, ssq);
  // K
  k_conv1x1<<<dim3(NN / 128, NC / 64, NB), 256, 0, stream>>>(Wk, x, Ysc);
  k_dwconv<<<dim3(4, NC, NB), 256, 0, stream>>>(Ysc, Wkd, (__hip_bfloat16*)bufB, ssk);
  // S + softmax
  k_attn<<<dim3(16, 16), 256, 0, stream>>>(bufA, bufB, S);
  k_softmax<<<16, 64, 0, stream>>>(S, ssq, ssk, Tmp, AT);
  // V reuses bufA
  k_conv1x1<<<dim3(NN / 128, NC / 64, NB), 256, 0, stream>>>(Wv, x, Ysc);
  k_dwconv<<<dim3(4, NC, NB), 256, 0, stream>>>(Ysc, Wvd, (__hip_bfloat16*)bufA, nullptr);
  k_out<<<dim3(NN / 512, 16), 256, 0, stream>>>(AT, (const __hip_bfloat16*)bufA, d_out, x);
}

// Round 4
// 269.706 us; speedup vs baseline: 1.2298x; 1.2298x over previous
//
#include <hip/hip_runtime.h>
#include <hip/hip_bf16.h>

// Restormer-style channel attention (MDTA). b=4, c=192, h=w=128 (n=16384),
// heads=4, ch=48. I/O is fp32 (runtime-detected, bf16 tolerated).
//
// Pipeline (ws ~76 MB of the ~268 MB available):
//   convert weights -> canonical bf16 | transpose+convert X -> Xt[b][n][c] bf16
//   per proj: conv1x1 MFMA (Xt staged as contiguous b128 tile) -> Y (d_out scratch)
//             dwconv3x3 (short8 io, 8 outputs/thread) -> P, sumsq for q,k
//   S = Q.K^T (MFMA over n, 16 chunks, atomics)
//   softmax with L2 norms + temperature folded (normalize commutes with dot)
//   out = attn . V  (K=48 skinny GEMM, short2 loads, float2 stores)

typedef __attribute__((ext_vector_type(8))) short short8;
typedef __attribute__((ext_vector_type(4))) float f32x4;

#define NB 4
#define NC 192
#define NN 16384
#define CH 48
#define NWELEM 115780   // 3*36864 + 3*1728 + 4 canonical weight elems

__device__ inline unsigned short f2bf(float f) {
  union { float f; unsigned int u; } c; c.f = f;
  unsigned int r = c.u + 0x7FFF + ((c.u >> 16) & 1);   // RNE
  return (unsigned short)(r >> 16);
}
__device__ inline float bf2f(unsigned short u) {
  union { unsigned int u; float f; } c; c.u = ((unsigned int)u) << 16;
  return c.f;
}

// fp32 (true) vs bf16 (false), wave-uniform. fp32 low-halves have random
// bf16 exponents (~70% extreme); real N(0,1) bf16 never does.
__device__ inline bool detect_f32(const unsigned short* x) {
  int l = threadIdx.x & 63;
  unsigned short u = x[2 * (l * 997 + 1)];
  int e = (u >> 7) & 0xFF;
  bool extreme = (e < 90) || (e > 165);
  return __popcll(__ballot(extreme)) >= 8;
}

// ------------------------------------------------------------ weight convert
__global__ __launch_bounds__(256) void k_convert(const unsigned short* __restrict__ x,
                                                 const void* wq, const void* wk, const void* wv,
                                                 const void* wqd, const void* wkd, const void* wvd,
                                                 const void* temp,
                                                 unsigned short* __restrict__ canon) {
  bool f32 = detect_f32(x);
  int i = blockIdx.x * 256 + threadIdx.x;
  if (i >= NWELEM) return;
  const void* src; int off;
  if (i < 36864)       { src = wq;  off = i; }
  else if (i < 73728)  { src = wk;  off = i - 36864; }
  else if (i < 110592) { src = wv;  off = i - 73728; }
  else if (i < 112320) { src = wqd; off = i - 110592; }
  else if (i < 114048) { src = wkd; off = i - 112320; }
  else if (i < 115776) { src = wvd; off = i - 114048; }
  else                 { src = temp; off = i - 115776; }
  canon[i] = f32 ? f2bf(((const float*)src)[off])
                 : ((const unsigned short*)src)[off];
}

// ------------------------------------------------------------ transpose+convert
// X[b][c][n] (fp32 or bf16) -> Xt[b][n][c] bf16. 64x64 tiles, 65-stride pad.
__global__ __launch_bounds__(256) void k_transpose(const unsigned short* __restrict__ X,
                                                   unsigned short* __restrict__ Xt) {
  __shared__ unsigned short tile[64 * 65];
  bool f32 = detect_f32(X);
  int b = blockIdx.z, c0 = blockIdx.y * 64, p0 = blockIdx.x * 64;
  int tid = threadIdx.x;
  if (f32) {
    const float* Xf = (const float*)X;
    for (int it = 0; it < 16; ++it) {
      int idx = it * 256 + tid;
      int c = idx >> 6, p = idx & 63;
      tile[c * 65 + p] = f2bf(Xf[((size_t)b * NC + c0 + c) * NN + p0 + p]);
    }
  } else {
    for (int it = 0; it < 16; ++it) {
      int idx = it * 256 + tid;
      int c = idx >> 6, p = idx & 63;
      tile[c * 65 + p] = X[((size_t)b * NC + c0 + c) * NN + p0 + p];
    }
  }
  __syncthreads();
  for (int it = 0; it < 2; ++it) {
    int idx = it * 256 + tid;
    int cc = idx & 7, p = idx >> 3;
    short8 v;
#pragma unroll
    for (int j = 0; j < 8; ++j) v[j] = (short)tile[(cc * 8 + j) * 65 + p];
    *(short8*)(Xt + ((size_t)b * NN + p0 + p) * NC + c0 + cc * 8) = v;
  }
}

// ------------------------------------------------------------ conv1x1 (MFMA)
// Y[b][d][p] = sum_c W[d][c] * Xt[b][p][c]. Tile 64d x 128p, K=192 full.
// Xt tile is a CONTIGUOUS 128*192 block -> pure b128 staging, no conflicts.
#define LDP 200   // padded LDS row stride (bf16 elems), 400B (16B-aligned)
__global__ __launch_bounds__(256) void k_conv1x1(const unsigned short* __restrict__ Wc,
                                                 const unsigned short* __restrict__ Xt,
                                                 unsigned short* __restrict__ Y) {
  __shared__ __align__(16) unsigned short Ws[64 * LDP];   // 25.6 KB
  __shared__ __align__(16) unsigned short Xs[128 * LDP];  // 51.2 KB
  int b = blockIdx.z, d0 = blockIdx.y * 64, p0 = blockIdx.x * 128;
  int tid = threadIdx.x;
  const unsigned short* tb = Xt + ((size_t)b * NN + p0) * NC;  // 128*192 contiguous
  for (int it = 0; it < 12; ++it) {
    int idx = it * 256 + tid;
    short8 v = *(const short8*)(tb + idx * 8);
    int p = idx / 24, cc = idx % 24;
    *(short8*)(&Xs[p * LDP + cc * 8]) = v;
  }
  const unsigned short* wb = Wc + d0 * NC;                     // 64*192 contiguous
  for (int it = 0; it < 6; ++it) {
    int idx = it * 256 + tid;
    short8 v = *(const short8*)(wb + idx * 8);
    int d = idx / 24, cc = idx % 24;
    *(short8*)(&Ws[d * LDP + cc * 8]) = v;
  }
  __syncthreads();
  int lane = tid & 63, w = tid >> 6;
  int wm = w & 1, wn = w >> 1;        // wave -> 32d x 64p quadrant
  int lrow = lane & 15, lq = lane >> 4;
  f32x4 acc[2][4];
  for (int mt = 0; mt < 2; ++mt)
    for (int nt = 0; nt < 4; ++nt) acc[mt][nt] = (f32x4){0.f, 0.f, 0.f, 0.f};
  for (int ks = 0; ks < 6; ++ks) {    // K = 192 = 6*32
    int k = ks * 32 + lq * 8;
    short8 a[2], bf[4];
    for (int mt = 0; mt < 2; ++mt)
      a[mt] = *(const short8*)(&Ws[(wm * 32 + mt * 16 + lrow) * LDP + k]);
    for (int nt = 0; nt < 4; ++nt)
      bf[nt] = *(const short8*)(&Xs[(wn * 64 + nt * 16 + lrow) * LDP + k]);
    for (int mt = 0; mt < 2; ++mt)
      for (int nt = 0; nt < 4; ++nt)
        acc[mt][nt] = __builtin_amdgcn_mfma_f32_16x16x32_bf16(a[mt], bf[nt], acc[mt][nt], 0, 0, 0);
  }
  // C/D: col = lane&15 (p), row = quad*4 + reg (d)
  for (int mt = 0; mt < 2; ++mt)
    for (int nt = 0; nt < 4; ++nt)
      for (int r = 0; r < 4; ++r) {
        int d = d0 + wm * 32 + mt * 16 + lq * 4 + r;
        int p = p0 + wn * 64 + nt * 16 + lrow;
        Y[((size_t)b * NC + d) * NN + p] = f2bf(acc[mt][nt][r]);
      }
}

// ------------------------------------------------------------ dwconv3x3 (+ sumsq)
// short8 global loads/stores, 8 outputs per thread. LDS fp32, data at col+2.
__global__ __launch_bounds__(256) void k_dwconv(const unsigned short* __restrict__ Y,
                                                const unsigned short* __restrict__ Wdc,
                                                unsigned short* __restrict__ P,
                                                float* __restrict__ ss) {
  __shared__ float Ys[34][132];   // 17.9 KB; data cols 2..129, halos 1 & 130
  __shared__ float red[4];
  int b = blockIdx.z, c = blockIdx.y, r0 = blockIdx.x * 32;
  int tid = threadIdx.x;
  const unsigned short* base = Y + ((size_t)b * NC + c) * NN;
  for (int it = 0; it < 3; ++it) {
    int t = it * 256 + tid;
    if (t < 544) {                 // 34 rows x 16 short8 chunks
      int r = t >> 4, ch = t & 15;
      int gr = r0 - 1 + r;
      float f[8];
      if (gr >= 0 && gr < 128) {
        short8 v = *(const short8*)(base + gr * 128 + ch * 8);
#pragma unroll
        for (int j = 0; j < 8; ++j) f[j] = bf2f((unsigned short)v[j]);
      } else {
#pragma unroll
        for (int j = 0; j < 8; ++j) f[j] = 0.f;
      }
#pragma unroll
      for (int j2 = 0; j2 < 4; ++j2)
        *(float2*)(&Ys[r][2 + ch * 8 + 2 * j2]) = make_float2(f[2 * j2], f[2 * j2 + 1]);
    }
  }
  if (tid < 34) { Ys[tid][1] = 0.f; Ys[tid][130] = 0.f; }
  float wk9[9];
  for (int i = 0; i < 9; ++i) wk9[i] = bf2f(Wdc[c * 9 + i]);
  __syncthreads();
  float ssacc = 0.f;
  for (int it = 0; it < 2; ++it) {   // 32 rows x 16 chunks
    int t = it * 256 + tid;
    int r = t >> 4, ch = t & 15;
    float z[8];
#pragma unroll
    for (int j = 0; j < 8; ++j) z[j] = 0.f;
#pragma unroll
    for (int dy = 0; dy < 3; ++dy) {
      float row[10];
#pragma unroll
      for (int t2 = 0; t2 < 10; ++t2) row[t2] = Ys[r + dy][1 + ch * 8 + t2];
#pragma unroll
      for (int dx = 0; dx < 3; ++dx) {
        float wv = wk9[dy * 3 + dx];
#pragma unroll
        for (int j = 0; j < 8; ++j) z[j] += wv * row[j + dx];
      }
    }
    short8 sv;
#pragma unroll
    for (int j = 0; j < 8; ++j) { sv[j] = (short)f2bf(z[j]); ssacc += z[j] * z[j]; }
    *(short8*)(P + ((size_t)b * NC + c) * NN + (r0 + r) * 128 + ch * 8) = sv;
  }
  if (ss) {
    for (int off = 32; off; off >>= 1) ssacc += __shfl_down(ssacc, off);
    if ((tid & 63) == 0) red[tid >> 6] = ssacc;
    __syncthreads();
    if (tid == 0) atomicAdd(&ss[b * NC + c], red[0] + red[1] + red[2] + red[3]);
  }
}

// ------------------------------------------------------------ S = Q.K^T
__global__ __launch_bounds__(256) void k_attn(const unsigned short* __restrict__ Qp,
                                              const unsigned short* __restrict__ Kp,
                                              float* __restrict__ S) {
  __shared__ float Sred[CH * CH];
  int bh = blockIdx.y, chunk = blockIdx.x;
  int b = bh >> 2, h = bh & 3;
  int tid = threadIdx.x, lane = tid & 63, w = tid >> 6;
  int lrow = lane & 15, lq = lane >> 4;
  const unsigned short* Qb = Qp + ((size_t)b * NC + h * CH) * NN;
  const unsigned short* Kb = Kp + ((size_t)b * NC + h * CH) * NN;
  int nbase = chunk * 1024 + w * 256;
  f32x4 acc[3][3];
  for (int i = 0; i < 3; ++i)
    for (int j = 0; j < 3; ++j) acc[i][j] = (f32x4){0.f, 0.f, 0.f, 0.f};
  for (int ks = 0; ks < 8; ++ks) {
    int n = nbase + ks * 32 + lq * 8;
    short8 a[3], bb[3];
    for (int t = 0; t < 3; ++t) a[t]  = *(const short8*)(Qb + (size_t)(t * 16 + lrow) * NN + n);
    for (int t = 0; t < 3; ++t) bb[t] = *(const short8*)(Kb + (size_t)(t * 16 + lrow) * NN + n);
    for (int ti = 0; ti < 3; ++ti)
      for (int tj = 0; tj < 3; ++tj)
        acc[ti][tj] = __builtin_amdgcn_mfma_f32_16x16x32_bf16(a[ti], bb[tj], acc[ti][tj], 0, 0, 0);
  }
  for (int i = tid; i < CH * CH; i += 256) Sred[i] = 0.f;
  __syncthreads();
  for (int ti = 0; ti < 3; ++ti)
    for (int tj = 0; tj < 3; ++tj)
      for (int r = 0; r < 4; ++r) {
        int row = ti * 16 + lq * 4 + r, col = tj * 16 + lrow;
        atomicAdd(&Sred[row * CH + col], acc[ti][tj][r]);
      }
  __syncthreads();
  float* Sg = S + bh * (CH * CH);
  for (int i = tid; i < CH * CH; i += 256) atomicAdd(&Sg[i], Sred[i]);
}

// ------------------------------------------------------------ softmax (+ norms)
__global__ void k_softmax(const float* __restrict__ S, const float* __restrict__ ssq,
                          const float* __restrict__ ssk, const unsigned short* __restrict__ tempc,
                          float* __restrict__ AT) {   // AT[bh][j][i]
  int bh = blockIdx.x, b = bh >> 2, h = bh & 3;
  int i = threadIdx.x;
  if (i >= CH) return;
  float t = bf2f(tempc[h]);
  float rq = 1.f / fmaxf(sqrtf(ssq[b * NC + h * CH + i]), 1e-12f);
  const float* Srow = S + bh * (CH * CH) + i * CH;
  float l[CH];
  float m = -1e30f;
  for (int j = 0; j < CH; ++j) {
    float rk = 1.f / fmaxf(sqrtf(ssk[b * NC + h * CH + j]), 1e-12f);
    l[j] = Srow[j] * rq * rk * t;
    m = fmaxf(m, l[j]);
  }
  float s = 0.f;
  for (int j = 0; j < CH; ++j) { l[j] = __expf(l[j] - m); s += l[j]; }
  float inv = 1.f / s;
  for (int j = 0; j < CH; ++j) AT[bh * (CH * CH) + j * CH + i] = l[j] * inv;
}

// ------------------------------------------------------------ out = attn . V
__global__ __launch_bounds__(256) void k_out(const float* __restrict__ AT,
                                             const unsigned short* __restrict__ Vp,
                                             void* __restrict__ Out,
                                             const unsigned short* __restrict__ x) {
  bool f32 = detect_f32(x);
  int bh = blockIdx.y, b = bh >> 2, h = bh & 3;
  int p0 = (blockIdx.x * 256 + threadIdx.x) * 2;   // short2 / float2 per thread
  const float* A = AT + bh * (CH * CH);            // [j][i], block-uniform
  const unsigned short* Vb = Vp + ((size_t)b * NC + h * CH) * NN;
  float a1[CH], a2[CH];
  for (int i = 0; i < CH; ++i) { a1[i] = 0.f; a2[i] = 0.f; }
  for (int j = 0; j < CH; ++j) {
    unsigned int u = *(const unsigned int*)(Vb + (size_t)j * NN + p0);
    float v1 = bf2f((unsigned short)(u & 0xFFFF));
    float v2 = bf2f((unsigned short)(u >> 16));
    const float* Aj = A + j * CH;
    for (int i = 0; i < CH; ++i) {
      float a = Aj[i];
      a1[i] += a * v1;
      a2[i] += a * v2;
    }
  }
  size_t obase = ((size_t)b * NC + h * CH) * NN;
  if (f32) {
    float* Of = (float*)Out;
    for (int i = 0; i < CH; ++i)
      *(float2*)(Of + obase + (size_t)i * NN + p0) = make_float2(a1[i], a2[i]);
  } else {
    unsigned short* Ob = (unsigned short*)Out;
    for (int i = 0; i < CH; ++i) {
      unsigned int u = ((unsigned int)f2bf(a2[i]) << 16) | f2bf(a1[i]);
      *(unsigned int*)(Ob + obase + (size_t)i * NN + p0) = u;
    }
  }
}

// ------------------------------------------------------------ launch
extern "C" void kernel_launch(void* const* d_in, const int* in_sizes, int n_in,
                              void* d_out, int out_size, void* d_ws, size_t ws_size,
                              hipStream_t stream) {
  const unsigned short* x = (const unsigned short*)d_in[0];

  const size_t TEN = (size_t)NB * NC * NN;   // 12,582,912 elems
  unsigned short* bufA = (unsigned short*)d_ws;   // Q', later V'
  unsigned short* bufB = bufA + TEN;              // K'
  unsigned short* Xt   = bufB + TEN;              // transposed X (bf16)
  float* ssq = (float*)(Xt + TEN);
  float* ssk = ssq + NB * NC;
  float* S   = ssk + NB * NC;
  float* AT  = S + 16 * CH * CH;
  unsigned short* canon = (unsigned short*)(AT + 16 * CH * CH);
  // ws total ~= 76 MB
  const unsigned short* Wq  = canon;
  const unsigned short* Wk  = canon + 36864;
  const unsigned short* Wv  = canon + 73728;
  const unsigned short* Wqd = canon + 110592;
  const unsigned short* Wkd = canon + 112320;
  const unsigned short* Wvd = canon + 114048;
  const unsigned short* Tmp = canon + 115776;

  hipMemsetAsync(ssq, 0, (2 * NB * NC + 16 * CH * CH) * sizeof(float), stream);
  k_convert<<<(NWELEM + 255) / 256, 256, 0, stream>>>(
      x, d_in[1], d_in[3], d_in[5], d_in[2], d_in[4], d_in[6], d_in[7], canon);
  k_transpose<<<dim3(NN / 64, NC / 64, NB), 256, 0, stream>>>(x, Xt);

  unsigned short* Ysc = (unsigned short*)d_out;   // Y scratch (bf16)

  // Q
  k_conv1x1<<<dim3(NN / 128, NC / 64, NB), 256, 0, stream>>>(Wq, Xt, Ysc);
  k_dwconv<<<dim3(4, NC, NB), 256, 0, stream>>>(Ysc, Wqd, bufA, ssq);
  // K
  k_conv1x1<<<dim3(NN / 128, NC / 64, NB), 256, 0, stream>>>(Wk, Xt, Ysc);
  k_dwconv<<<dim3(4, NC, NB), 256, 0, stream>>>(Ysc, Wkd, bufB, ssk);
  // S + softmax
  k_attn<<<dim3(16, 16), 256, 0, stream>>>(bufA, bufB, S);
  k_softmax<<<16, 64, 0, stream>>>(S, ssq, ssk, Tmp, AT);
  // V reuses bufA
  k_conv1x1<<<dim3(NN / 128, NC / 64, NB), 256, 0, stream>>>(Wv, Xt, Ysc);
  k_dwconv<<<dim3(4, NC, NB), 256, 0, stream>>>(Ysc, Wvd, bufA, nullptr);
  k_out<<<dim3(NN / 512, 16), 256, 0, stream>>>(AT, bufA, d_out, x);
}

// Round 5
// 258.496 us; speedup vs baseline: 1.2831x; 1.0434x over previous
//
#include <hip/hip_runtime.h>
#include <hip/hip_bf16.h>

// Restormer-style channel attention (MDTA). b=4, c=192, h=w=128 (n=16384),
// heads=4, ch=48. I/O fp32 (runtime-detected, bf16 tolerated).
//
// 6 launches:
//   k_pre:       weights -> canonical bf16 (Wq|Wk|Wv = one 576x192 matrix),
//                zero ssq/ssk/S
//   k_transpose: X[b][c][n] fp32 -> Xt[b][n][c] bf16 (64x64 tiles, pad 65)
//   k_conv:      fused q|k|v conv1x1 MFMA; Xt tile staged once, 9 d-tiles,
//                W frags from L2 -> Yall[proj][b][c][n]
//   k_dwconv:    fused q|k|v depthwise 3x3 (short8 io), sumsq for q,k
//   k_attn:      S = Q.K^T (MFMA over n, 16 chunks, atomics)
//   k_softmax:   fold L2 norms + temperature (normalize commutes with dot)
//   k_out:       out = attn . V (K=48 skinny GEMM, fp32 out)

typedef __attribute__((ext_vector_type(8))) short short8;
typedef __attribute__((ext_vector_type(4))) float f32x4;

#define NB 4
#define NC 192
#define NN 16384
#define CH 48
#define NWELEM 115780     // 3*36864 + 3*1728 + 4
#define NZERO 38400       // ssq(768) + ssk(768) + S(16*48*48) floats

__device__ inline unsigned short f2bf(float f) {
  union { float f; unsigned int u; } c; c.f = f;
  unsigned int r = c.u + 0x7FFF + ((c.u >> 16) & 1);   // RNE
  return (unsigned short)(r >> 16);
}
__device__ inline float bf2f(unsigned short u) {
  union { unsigned int u; float f; } c; c.u = ((unsigned int)u) << 16;
  return c.f;
}

// fp32 (true) vs bf16 (false), wave-uniform.
__device__ inline bool detect_f32(const unsigned short* x) {
  int l = threadIdx.x & 63;
  unsigned short u = x[2 * (l * 997 + 1)];
  int e = (u >> 7) & 0xFF;
  bool extreme = (e < 90) || (e > 165);
  return __popcll(__ballot(extreme)) >= 8;
}

// ------------------------------------------------------------ pre: convert + zero
__global__ __launch_bounds__(256) void k_pre(const unsigned short* __restrict__ x,
                                             const void* wq, const void* wk, const void* wv,
                                             const void* wqd, const void* wkd, const void* wvd,
                                             const void* temp,
                                             unsigned short* __restrict__ canon,
                                             float* __restrict__ zbase) {
  int blk = blockIdx.x;
  if (blk >= 453) {   // zero range
    int i = (blk - 453) * 256 + threadIdx.x;
    if (i < NZERO) zbase[i] = 0.f;
    return;
  }
  bool f32 = detect_f32(x);
  int i = blk * 256 + threadIdx.x;
  if (i >= NWELEM) return;
  const void* src; int off;
  if (i < 36864)       { src = wq;  off = i; }
  else if (i < 73728)  { src = wk;  off = i - 36864; }
  else if (i < 110592) { src = wv;  off = i - 73728; }
  else if (i < 112320) { src = wqd; off = i - 110592; }
  else if (i < 114048) { src = wkd; off = i - 112320; }
  else if (i < 115776) { src = wvd; off = i - 114048; }
  else                 { src = temp; off = i - 115776; }
  canon[i] = f32 ? f2bf(((const float*)src)[off])
                 : ((const unsigned short*)src)[off];
}

// ------------------------------------------------------------ transpose+convert
__global__ __launch_bounds__(256) void k_transpose(const unsigned short* __restrict__ X,
                                                   unsigned short* __restrict__ Xt) {
  __shared__ unsigned short tile[64 * 65];
  bool f32 = detect_f32(X);
  int b = blockIdx.z, c0 = blockIdx.y * 64, p0 = blockIdx.x * 64;
  int tid = threadIdx.x;
  if (f32) {
    const float* Xf = (const float*)X;
    for (int it = 0; it < 16; ++it) {
      int idx = it * 256 + tid;
      int c = idx >> 6, p = idx & 63;
      tile[c * 65 + p] = f2bf(Xf[((size_t)b * NC + c0 + c) * NN + p0 + p]);
    }
  } else {
    for (int it = 0; it < 16; ++it) {
      int idx = it * 256 + tid;
      int c = idx >> 6, p = idx & 63;
      tile[c * 65 + p] = X[((size_t)b * NC + c0 + c) * NN + p0 + p];
    }
  }
  __syncthreads();
  for (int it = 0; it < 2; ++it) {
    int idx = it * 256 + tid;
    int cc = idx & 7, p = idx >> 3;
    short8 v;
#pragma unroll
    for (int j = 0; j < 8; ++j) v[j] = (short)tile[(cc * 8 + j) * 65 + p];
    *(short8*)(Xt + ((size_t)b * NN + p0 + p) * NC + c0 + cc * 8) = v;
  }
}

// ------------------------------------------------------------ fused conv1x1 (MFMA)
// Yall[proj][b][d][p] = sum_c Wall[proj*192+d][c] * Xt[b][p][c]
// One block: stage 128p x 192c Xt tile once, loop 9 d-tiles of 64.
#define LDP 200
__global__ __launch_bounds__(256) void k_conv(const unsigned short* __restrict__ Wall,
                                              const unsigned short* __restrict__ Xt,
                                              unsigned short* __restrict__ Yall) {
  __shared__ __align__(16) unsigned short Xs[128 * LDP];  // 51.2 KB
  int b = blockIdx.y, p0 = blockIdx.x * 128;
  int tid = threadIdx.x;
  const unsigned short* tb = Xt + ((size_t)b * NN + p0) * NC;  // contiguous 48KB
  for (int it = 0; it < 12; ++it) {
    int idx = it * 256 + tid;
    short8 v = *(const short8*)(tb + idx * 8);
    int p = idx / 24, cc = idx % 24;
    *(short8*)(&Xs[p * LDP + cc * 8]) = v;
  }
  __syncthreads();
  int lane = tid & 63, w = tid >> 6;
  int wm = w & 1, wn = w >> 1;        // wave -> 32d x 64p quadrant
  int lrow = lane & 15, lq = lane >> 4;
  // preload this wave's B-frags for all 6 k-steps (24 VGPR-quads, reused 9x)
  short8 bf[6][4];
  for (int ks = 0; ks < 6; ++ks)
    for (int nt = 0; nt < 4; ++nt)
      bf[ks][nt] = *(const short8*)(&Xs[(wn * 64 + nt * 16 + lrow) * LDP + ks * 32 + lq * 8]);
  for (int dt = 0; dt < 9; ++dt) {    // 9 d-tiles of 64 over 576 rows
    int d0 = dt * 64;
    f32x4 acc[2][4];
    for (int mt = 0; mt < 2; ++mt)
      for (int nt = 0; nt < 4; ++nt) acc[mt][nt] = (f32x4){0.f, 0.f, 0.f, 0.f};
    for (int ks = 0; ks < 6; ++ks) {
      int k = ks * 32 + lq * 8;
      short8 a[2];
      for (int mt = 0; mt < 2; ++mt)
        a[mt] = *(const short8*)(Wall + (size_t)(d0 + wm * 32 + mt * 16 + lrow) * NC + k);
      for (int mt = 0; mt < 2; ++mt)
        for (int nt = 0; nt < 4; ++nt)
          acc[mt][nt] = __builtin_amdgcn_mfma_f32_16x16x32_bf16(a[mt], bf[ks][nt], acc[mt][nt], 0, 0, 0);
    }
    int proj = dt / 3, c0 = (dt % 3) * 64;
    unsigned short* Yb = Yall + (((size_t)proj * NB + b) * NC) * NN;
    for (int mt = 0; mt < 2; ++mt)
      for (int nt = 0; nt < 4; ++nt)
        for (int r = 0; r < 4; ++r) {
          int c = c0 + wm * 32 + mt * 16 + lq * 4 + r;
          int p = p0 + wn * 64 + nt * 16 + lrow;
          Yb[(size_t)c * NN + p] = f2bf(acc[mt][nt][r]);
        }
  }
}

// ------------------------------------------------------------ fused dwconv3x3 (+ sumsq)
__global__ __launch_bounds__(256) void k_dwconv(const unsigned short* __restrict__ Yall,
                                                const unsigned short* __restrict__ Wdall,
                                                unsigned short* __restrict__ Pq,
                                                unsigned short* __restrict__ Pk,
                                                unsigned short* __restrict__ Pv,
                                                float* __restrict__ ssq,
                                                float* __restrict__ ssk) {
  __shared__ float Ys[34][132];
  __shared__ float red[4];
  int b = blockIdx.z, y = blockIdx.y, r0 = blockIdx.x * 32;
  int proj = y / NC, c = y % NC;
  int tid = threadIdx.x;
  const unsigned short* base = Yall + (((size_t)proj * NB + b) * NC + c) * NN;
  unsigned short* P = (proj == 0 ? Pq : (proj == 1 ? Pk : Pv));
  float* ss = (proj == 0 ? ssq : (proj == 1 ? ssk : nullptr));
  for (int it = 0; it < 3; ++it) {
    int t = it * 256 + tid;
    if (t < 544) {                 // 34 rows x 16 short8 chunks
      int r = t >> 4, ch = t & 15;
      int gr = r0 - 1 + r;
      float f[8];
      if (gr >= 0 && gr < 128) {
        short8 v = *(const short8*)(base + gr * 128 + ch * 8);
#pragma unroll
        for (int j = 0; j < 8; ++j) f[j] = bf2f((unsigned short)v[j]);
      } else {
#pragma unroll
        for (int j = 0; j < 8; ++j) f[j] = 0.f;
      }
#pragma unroll
      for (int j2 = 0; j2 < 4; ++j2)
        *(float2*)(&Ys[r][2 + ch * 8 + 2 * j2]) = make_float2(f[2 * j2], f[2 * j2 + 1]);
    }
  }
  if (tid < 34) { Ys[tid][1] = 0.f; Ys[tid][130] = 0.f; }
  float wk9[9];
  for (int i = 0; i < 9; ++i) wk9[i] = bf2f(Wdall[(proj * NC + c) * 9 + i]);
  __syncthreads();
  float ssacc = 0.f;
  for (int it = 0; it < 2; ++it) {   // 32 rows x 16 chunks
    int t = it * 256 + tid;
    int r = t >> 4, ch = t & 15;
    float z[8];
#pragma unroll
    for (int j = 0; j < 8; ++j) z[j] = 0.f;
#pragma unroll
    for (int dy = 0; dy < 3; ++dy) {
      float row[10];
#pragma unroll
      for (int t2 = 0; t2 < 10; ++t2) row[t2] = Ys[r + dy][1 + ch * 8 + t2];
#pragma unroll
      for (int dx = 0; dx < 3; ++dx) {
        float wv = wk9[dy * 3 + dx];
#pragma unroll
        for (int j = 0; j < 8; ++j) z[j] += wv * row[j + dx];
      }
    }
    short8 sv;
#pragma unroll
    for (int j = 0; j < 8; ++j) { sv[j] = (short)f2bf(z[j]); ssacc += z[j] * z[j]; }
    *(short8*)(P + ((size_t)b * NC + c) * NN + (r0 + r) * 128 + ch * 8) = sv;
  }
  if (ss) {
    for (int off = 32; off; off >>= 1) ssacc += __shfl_down(ssacc, off);
    if ((tid & 63) == 0) red[tid >> 6] = ssacc;
    __syncthreads();
    if (tid == 0) atomicAdd(&ss[b * NC + c], red[0] + red[1] + red[2] + red[3]);
  }
}

// ------------------------------------------------------------ S = Q.K^T
__global__ __launch_bounds__(256) void k_attn(const unsigned short* __restrict__ Qp,
                                              const unsigned short* __restrict__ Kp,
                                              float* __restrict__ S) {
  __shared__ float Sred[CH * CH];
  int bh = blockIdx.y, chunk = blockIdx.x;
  int b = bh >> 2, h = bh & 3;
  int tid = threadIdx.x, lane = tid & 63, w = tid >> 6;
  int lrow = lane & 15, lq = lane >> 4;
  const unsigned short* Qb = Qp + ((size_t)b * NC + h * CH) * NN;
  const unsigned short* Kb = Kp + ((size_t)b * NC + h * CH) * NN;
  int nbase = chunk * 1024 + w * 256;
  f32x4 acc[3][3];
  for (int i = 0; i < 3; ++i)
    for (int j = 0; j < 3; ++j) acc[i][j] = (f32x4){0.f, 0.f, 0.f, 0.f};
  for (int ks = 0; ks < 8; ++ks) {
    int n = nbase + ks * 32 + lq * 8;
    short8 a[3], bb[3];
    for (int t = 0; t < 3; ++t) a[t]  = *(const short8*)(Qb + (size_t)(t * 16 + lrow) * NN + n);
    for (int t = 0; t < 3; ++t) bb[t] = *(const short8*)(Kb + (size_t)(t * 16 + lrow) * NN + n);
    for (int ti = 0; ti < 3; ++ti)
      for (int tj = 0; tj < 3; ++tj)
        acc[ti][tj] = __builtin_amdgcn_mfma_f32_16x16x32_bf16(a[ti], bb[tj], acc[ti][tj], 0, 0, 0);
  }
  for (int i = tid; i < CH * CH; i += 256) Sred[i] = 0.f;
  __syncthreads();
  for (int ti = 0; ti < 3; ++ti)
    for (int tj = 0; tj < 3; ++tj)
      for (int r = 0; r < 4; ++r) {
        int row = ti * 16 + lq * 4 + r, col = tj * 16 + lrow;
        atomicAdd(&Sred[row * CH + col], acc[ti][tj][r]);
      }
  __syncthreads();
  float* Sg = S + bh * (CH * CH);
  for (int i = tid; i < CH * CH; i += 256) atomicAdd(&Sg[i], Sred[i]);
}

// ------------------------------------------------------------ softmax (+ norms)
__global__ void k_softmax(const float* __restrict__ S, const float* __restrict__ ssq,
                          const float* __restrict__ ssk, const unsigned short* __restrict__ tempc,
                          float* __restrict__ AT) {   // AT[bh][j][i]
  int bh = blockIdx.x, b = bh >> 2, h = bh & 3;
  int i = threadIdx.x;
  if (i >= CH) return;
  float t = bf2f(tempc[h]);
  float rq = 1.f / fmaxf(sqrtf(ssq[b * NC + h * CH + i]), 1e-12f);
  const float* Srow = S + bh * (CH * CH) + i * CH;
  float l[CH];
  float m = -1e30f;
  for (int j = 0; j < CH; ++j) {
    float rk = 1.f / fmaxf(sqrtf(ssk[b * NC + h * CH + j]), 1e-12f);
    l[j] = Srow[j] * rq * rk * t;
    m = fmaxf(m, l[j]);
  }
  float s = 0.f;
  for (int j = 0; j < CH; ++j) { l[j] = __expf(l[j] - m); s += l[j]; }
  float inv = 1.f / s;
  for (int j = 0; j < CH; ++j) AT[bh * (CH * CH) + j * CH + i] = l[j] * inv;
}

// ------------------------------------------------------------ out = attn . V
__global__ __launch_bounds__(256) void k_out(const float* __restrict__ AT,
                                             const unsigned short* __restrict__ Vp,
                                             void* __restrict__ Out,
                                             const unsigned short* __restrict__ x) {
  bool f32 = detect_f32(x);
  int bh = blockIdx.y, b = bh >> 2, h = bh & 3;
  int p0 = (blockIdx.x * 256 + threadIdx.x) * 2;
  const float* A = AT + bh * (CH * CH);            // [j][i], block-uniform
  const unsigned short* Vb = Vp + ((size_t)b * NC + h * CH) * NN;
  float a1[CH], a2[CH];
  for (int i = 0; i < CH; ++i) { a1[i] = 0.f; a2[i] = 0.f; }
  for (int j = 0; j < CH; ++j) {
    unsigned int u = *(const unsigned int*)(Vb + (size_t)j * NN + p0);
    float v1 = bf2f((unsigned short)(u & 0xFFFF));
    float v2 = bf2f((unsigned short)(u >> 16));
    const float* Aj = A + j * CH;
    for (int i = 0; i < CH; ++i) {
      float a = Aj[i];
      a1[i] += a * v1;
      a2[i] += a * v2;
    }
  }
  size_t obase = ((size_t)b * NC + h * CH) * NN;
  if (f32) {
    float* Of = (float*)Out;
    for (int i = 0; i < CH; ++i)
      *(float2*)(Of + obase + (size_t)i * NN + p0) = make_float2(a1[i], a2[i]);
  } else {
    unsigned short* Ob = (unsigned short*)Out;
    for (int i = 0; i < CH; ++i) {
      unsigned int u = ((unsigned int)f2bf(a2[i]) << 16) | f2bf(a1[i]);
      *(unsigned int*)(Ob + obase + (size_t)i * NN + p0) = u;
    }
  }
}

// ------------------------------------------------------------ launch
extern "C" void kernel_launch(void* const* d_in, const int* in_sizes, int n_in,
                              void* d_out, int out_size, void* d_ws, size_t ws_size,
                              hipStream_t stream) {
  const unsigned short* x = (const unsigned short*)d_in[0];

  const size_t TEN = (size_t)NB * NC * NN;   // 12,582,912 elems
  unsigned short* bufA = (unsigned short*)d_ws;   // Q'
  unsigned short* bufB = bufA + TEN;              // K'
  unsigned short* bufV = bufB + TEN;              // V'
  unsigned short* Xt   = bufV + TEN;              // X transposed (bf16)
  unsigned short* Yall = Xt + TEN;                // 3 conv outputs (75.5 MB)
  float* ssq = (float*)(Yall + 3 * TEN);
  float* ssk = ssq + NB * NC;
  float* S   = ssk + NB * NC;
  float* AT  = S + 16 * CH * CH;
  unsigned short* canon = (unsigned short*)(AT + 16 * CH * CH);
  // ws total ~= 176.6 MB (< 268 MB)
  const unsigned short* Wall = canon;             // Wq|Wk|Wv = 576x192
  const unsigned short* Wdall = canon + 110592;   // wqd|wkd|wvd = 576x9
  const unsigned short* Tmp = canon + 115776;

  k_pre<<<453 + (NZERO + 255) / 256, 256, 0, stream>>>(
      x, d_in[1], d_in[3], d_in[5], d_in[2], d_in[4], d_in[6], d_in[7], canon, ssq);
  k_transpose<<<dim3(NN / 64, NC / 64, NB), 256, 0, stream>>>(x, Xt);
  k_conv<<<dim3(NN / 128, NB), 256, 0, stream>>>(Wall, Xt, Yall);
  k_dwconv<<<dim3(4, 3 * NC, NB), 256, 0, stream>>>(Yall, Wdall, bufA, bufB, bufV, ssq, ssk);
  k_attn<<<dim3(16, 16), 256, 0, stream>>>(bufA, bufB, S);
  k_softmax<<<16, 64, 0, stream>>>(S, ssq, ssk, Tmp, AT);
  k_out<<<dim3(NN / 512, 16), 256, 0, stream>>>(AT, bufV, d_out, x);
}

// Round 6
// 253.735 us; speedup vs baseline: 1.3072x; 1.0188x over previous
//
#include <hip/hip_runtime.h>
#include <hip/hip_bf16.h>

// Restormer-style channel attention (MDTA). b=4, c=192, h=w=128 (n=16384),
// heads=4, ch=48. I/O fp32 (runtime-detected, bf16 tolerated).
//
// Launches:
//   k_pre:       weights -> canonical bf16 (Wq|Wk|Wv = one 576x192 matrix),
//                zero ssq/ssk/S
//   k_transpose: X[b][c][n] fp32 -> Xt[b][n][c] bf16 (64x64 tiles, pad 65)
//   k_conv:      fused q|k|v conv1x1 MFMA; Xt tile staged once, 9 d-tiles,
//                W frags from L2 -> Yall[proj][b][c][n]
//   k_dwconv:    fused q|k|v depthwise 3x3 — LDS-FREE: 3 aligned short8 rows
//                per thread from global (L1 absorbs 3x vertical reuse),
//                column halo via __shfl from lane neighbors, wave-reduced sumsq
//   k_attn:      S = Q.K^T (MFMA over n, 16 chunks, atomics)
//   k_softmax:   fold L2 norms + temperature (normalize commutes with dot)
//   k_out:       out = attn . V (K=48 skinny GEMM, fp32 out)

typedef __attribute__((ext_vector_type(8))) short short8;
typedef __attribute__((ext_vector_type(4))) float f32x4;

#define NB 4
#define NC 192
#define NN 16384
#define CH 48
#define NWELEM 115780     // 3*36864 + 3*1728 + 4
#define NZERO 38400       // ssq(768) + ssk(768) + S(16*48*48) floats

__device__ inline unsigned short f2bf(float f) {
  union { float f; unsigned int u; } c; c.f = f;
  unsigned int r = c.u + 0x7FFF + ((c.u >> 16) & 1);   // RNE
  return (unsigned short)(r >> 16);
}
__device__ inline float bf2f(unsigned short u) {
  union { unsigned int u; float f; } c; c.u = ((unsigned int)u) << 16;
  return c.f;
}

// fp32 (true) vs bf16 (false), wave-uniform.
__device__ inline bool detect_f32(const unsigned short* x) {
  int l = threadIdx.x & 63;
  unsigned short u = x[2 * (l * 997 + 1)];
  int e = (u >> 7) & 0xFF;
  bool extreme = (e < 90) || (e > 165);
  return __popcll(__ballot(extreme)) >= 8;
}

// ------------------------------------------------------------ pre: convert + zero
__global__ __launch_bounds__(256) void k_pre(const unsigned short* __restrict__ x,
                                             const void* wq, const void* wk, const void* wv,
                                             const void* wqd, const void* wkd, const void* wvd,
                                             const void* temp,
                                             unsigned short* __restrict__ canon,
                                             float* __restrict__ zbase) {
  int blk = blockIdx.x;
  if (blk >= 453) {   // zero range
    int i = (blk - 453) * 256 + threadIdx.x;
    if (i < NZERO) zbase[i] = 0.f;
    return;
  }
  bool f32 = detect_f32(x);
  int i = blk * 256 + threadIdx.x;
  if (i >= NWELEM) return;
  const void* src; int off;
  if (i < 36864)       { src = wq;  off = i; }
  else if (i < 73728)  { src = wk;  off = i - 36864; }
  else if (i < 110592) { src = wv;  off = i - 73728; }
  else if (i < 112320) { src = wqd; off = i - 110592; }
  else if (i < 114048) { src = wkd; off = i - 112320; }
  else if (i < 115776) { src = wvd; off = i - 114048; }
  else                 { src = temp; off = i - 115776; }
  canon[i] = f32 ? f2bf(((const float*)src)[off])
                 : ((const unsigned short*)src)[off];
}

// ------------------------------------------------------------ transpose+convert
__global__ __launch_bounds__(256) void k_transpose(const unsigned short* __restrict__ X,
                                                   unsigned short* __restrict__ Xt) {
  __shared__ unsigned short tile[64 * 65];
  bool f32 = detect_f32(X);
  int b = blockIdx.z, c0 = blockIdx.y * 64, p0 = blockIdx.x * 64;
  int tid = threadIdx.x;
  if (f32) {
    const float* Xf = (const float*)X;
    for (int it = 0; it < 16; ++it) {
      int idx = it * 256 + tid;
      int c = idx >> 6, p = idx & 63;
      tile[c * 65 + p] = f2bf(Xf[((size_t)b * NC + c0 + c) * NN + p0 + p]);
    }
  } else {
    for (int it = 0; it < 16; ++it) {
      int idx = it * 256 + tid;
      int c = idx >> 6, p = idx & 63;
      tile[c * 65 + p] = X[((size_t)b * NC + c0 + c) * NN + p0 + p];
    }
  }
  __syncthreads();
  for (int it = 0; it < 2; ++it) {
    int idx = it * 256 + tid;
    int cc = idx & 7, p = idx >> 3;
    short8 v;
#pragma unroll
    for (int j = 0; j < 8; ++j) v[j] = (short)tile[(cc * 8 + j) * 65 + p];
    *(short8*)(Xt + ((size_t)b * NN + p0 + p) * NC + c0 + cc * 8) = v;
  }
}

// ------------------------------------------------------------ fused conv1x1 (MFMA)
// Yall[proj][b][d][p] = sum_c Wall[proj*192+d][c] * Xt[b][p][c]
#define LDP 200
__global__ __launch_bounds__(256) void k_conv(const unsigned short* __restrict__ Wall,
                                              const unsigned short* __restrict__ Xt,
                                              unsigned short* __restrict__ Yall) {
  __shared__ __align__(16) unsigned short Xs[128 * LDP];  // 51.2 KB
  int b = blockIdx.y, p0 = blockIdx.x * 128;
  int tid = threadIdx.x;
  const unsigned short* tb = Xt + ((size_t)b * NN + p0) * NC;  // contiguous 48KB
  for (int it = 0; it < 12; ++it) {
    int idx = it * 256 + tid;
    short8 v = *(const short8*)(tb + idx * 8);
    int p = idx / 24, cc = idx % 24;
    *(short8*)(&Xs[p * LDP + cc * 8]) = v;
  }
  __syncthreads();
  int lane = tid & 63, w = tid >> 6;
  int wm = w & 1, wn = w >> 1;        // wave -> 32d x 64p quadrant
  int lrow = lane & 15, lq = lane >> 4;
  // preload this wave's B-frags for all 6 k-steps (reused 9x)
  short8 bf[6][4];
  for (int ks = 0; ks < 6; ++ks)
    for (int nt = 0; nt < 4; ++nt)
      bf[ks][nt] = *(const short8*)(&Xs[(wn * 64 + nt * 16 + lrow) * LDP + ks * 32 + lq * 8]);
  for (int dt = 0; dt < 9; ++dt) {    // 9 d-tiles of 64 over 576 rows
    int d0 = dt * 64;
    f32x4 acc[2][4];
    for (int mt = 0; mt < 2; ++mt)
      for (int nt = 0; nt < 4; ++nt) acc[mt][nt] = (f32x4){0.f, 0.f, 0.f, 0.f};
    for (int ks = 0; ks < 6; ++ks) {
      int k = ks * 32 + lq * 8;
      short8 a[2];
      for (int mt = 0; mt < 2; ++mt)
        a[mt] = *(const short8*)(Wall + (size_t)(d0 + wm * 32 + mt * 16 + lrow) * NC + k);
      for (int mt = 0; mt < 2; ++mt)
        for (int nt = 0; nt < 4; ++nt)
          acc[mt][nt] = __builtin_amdgcn_mfma_f32_16x16x32_bf16(a[mt], bf[ks][nt], acc[mt][nt], 0, 0, 0);
    }
    int proj = dt / 3, c0 = (dt % 3) * 64;
    unsigned short* Yb = Yall + (((size_t)proj * NB + b) * NC) * NN;
    for (int mt = 0; mt < 2; ++mt)
      for (int nt = 0; nt < 4; ++nt)
        for (int r = 0; r < 4; ++r) {
          int c = c0 + wm * 32 + mt * 16 + lq * 4 + r;
          int p = p0 + wn * 64 + nt * 16 + lrow;
          Yb[(size_t)c * NN + p] = f2bf(acc[mt][nt][r]);
        }
  }
}

// ------------------------------------------------------------ fused dwconv3x3 (+ sumsq)
// LDS-free: per thread one 8-wide chunk, 3 aligned short8 global loads
// (L1 absorbs vertical reuse), column halo via lane shuffles.
__global__ __launch_bounds__(256) void k_dwconv(const unsigned short* __restrict__ Yall,
                                                const unsigned short* __restrict__ Wdall,
                                                unsigned short* __restrict__ Pq,
                                                unsigned short* __restrict__ Pk,
                                                unsigned short* __restrict__ Pv,
                                                float* __restrict__ ssq,
                                                float* __restrict__ ssk) {
  int b = blockIdx.z, y = blockIdx.y, r0 = blockIdx.x * 32;
  int proj = y / NC, c = y % NC;
  int tid = threadIdx.x;
  int lane = tid & 63, ch = tid & 15;
  const unsigned short* base = Yall + (((size_t)proj * NB + b) * NC + c) * NN;
  unsigned short* P = (proj == 0 ? Pq : (proj == 1 ? Pk : Pv));
  float* ss = (proj == 0 ? ssq : (proj == 1 ? ssk : nullptr));
  float wk9[9];
#pragma unroll
  for (int i = 0; i < 9; ++i) wk9[i] = bf2f(Wdall[(proj * NC + c) * 9 + i]);
  float ssacc = 0.f;
#pragma unroll
  for (int it = 0; it < 2; ++it) {     // 2 x (16 rows x 16 chunks)
    int t = it * 256 + tid;
    int r = t >> 4;                    // 0..31 output row (local)
    int gr = r0 + r;
    float z[8];
#pragma unroll
    for (int j = 0; j < 8; ++j) z[j] = 0.f;
#pragma unroll
    for (int dy = 0; dy < 3; ++dy) {
      int gy = gr - 1 + dy;
      float f[8];
      if (gy >= 0 && gy < 128) {
        short8 v = *(const short8*)(base + gy * 128 + ch * 8);
#pragma unroll
        for (int j = 0; j < 8; ++j) f[j] = bf2f((unsigned short)v[j]);
      } else {
#pragma unroll
        for (int j = 0; j < 8; ++j) f[j] = 0.f;
      }
      float lf = __shfl(f[7], lane - 1);
      float rf = __shfl(f[0], lane + 1);
      if (ch == 0)  lf = 0.f;
      if (ch == 15) rf = 0.f;
      float w0 = wk9[dy * 3], w1 = wk9[dy * 3 + 1], w2 = wk9[dy * 3 + 2];
      z[0] += w0 * lf + w1 * f[0] + w2 * f[1];
#pragma unroll
      for (int j = 1; j < 7; ++j) z[j] += w0 * f[j - 1] + w1 * f[j] + w2 * f[j + 1];
      z[7] += w0 * f[6] + w1 * f[7] + w2 * rf;
    }
    short8 sv;
#pragma unroll
    for (int j = 0; j < 8; ++j) { sv[j] = (short)f2bf(z[j]); ssacc += z[j] * z[j]; }
    *(short8*)(P + ((size_t)b * NC + c) * NN + gr * 128 + ch * 8) = sv;
  }
  if (ss) {
    for (int off = 32; off; off >>= 1) ssacc += __shfl_down(ssacc, off);
    if (lane == 0) atomicAdd(&ss[b * NC + c], ssacc);
  }
}

// ------------------------------------------------------------ S = Q.K^T
__global__ __launch_bounds__(256) void k_attn(const unsigned short* __restrict__ Qp,
                                              const unsigned short* __restrict__ Kp,
                                              float* __restrict__ S) {
  __shared__ float Sred[CH * CH];
  int bh = blockIdx.y, chunk = blockIdx.x;
  int b = bh >> 2, h = bh & 3;
  int tid = threadIdx.x, lane = tid & 63, w = tid >> 6;
  int lrow = lane & 15, lq = lane >> 4;
  const unsigned short* Qb = Qp + ((size_t)b * NC + h * CH) * NN;
  const unsigned short* Kb = Kp + ((size_t)b * NC + h * CH) * NN;
  int nbase = chunk * 1024 + w * 256;
  f32x4 acc[3][3];
  for (int i = 0; i < 3; ++i)
    for (int j = 0; j < 3; ++j) acc[i][j] = (f32x4){0.f, 0.f, 0.f, 0.f};
  for (int ks = 0; ks < 8; ++ks) {
    int n = nbase + ks * 32 + lq * 8;
    short8 a[3], bb[3];
    for (int t = 0; t < 3; ++t) a[t]  = *(const short8*)(Qb + (size_t)(t * 16 + lrow) * NN + n);
    for (int t = 0; t < 3; ++t) bb[t] = *(const short8*)(Kb + (size_t)(t * 16 + lrow) * NN + n);
    for (int ti = 0; ti < 3; ++ti)
      for (int tj = 0; tj < 3; ++tj)
        acc[ti][tj] = __builtin_amdgcn_mfma_f32_16x16x32_bf16(a[ti], bb[tj], acc[ti][tj], 0, 0, 0);
  }
  for (int i = tid; i < CH * CH; i += 256) Sred[i] = 0.f;
  __syncthreads();
  for (int ti = 0; ti < 3; ++ti)
    for (int tj = 0; tj < 3; ++tj)
      for (int r = 0; r < 4; ++r) {
        int row = ti * 16 + lq * 4 + r, col = tj * 16 + lrow;
        atomicAdd(&Sred[row * CH + col], acc[ti][tj][r]);
      }
  __syncthreads();
  float* Sg = S + bh * (CH * CH);
  for (int i = tid; i < CH * CH; i += 256) atomicAdd(&Sg[i], Sred[i]);
}

// ------------------------------------------------------------ softmax (+ norms)
__global__ void k_softmax(const float* __restrict__ S, const float* __restrict__ ssq,
                          const float* __restrict__ ssk, const unsigned short* __restrict__ tempc,
                          float* __restrict__ AT) {   // AT[bh][j][i]
  int bh = blockIdx.x, b = bh >> 2, h = bh & 3;
  int i = threadIdx.x;
  if (i >= CH) return;
  float t = bf2f(tempc[h]);
  float rq = 1.f / fmaxf(sqrtf(ssq[b * NC + h * CH + i]), 1e-12f);
  const float* Srow = S + bh * (CH * CH) + i * CH;
  float l[CH];
  float m = -1e30f;
  for (int j = 0; j < CH; ++j) {
    float rk = 1.f / fmaxf(sqrtf(ssk[b * NC + h * CH + j]), 1e-12f);
    l[j] = Srow[j] * rq * rk * t;
    m = fmaxf(m, l[j]);
  }
  float s = 0.f;
  for (int j = 0; j < CH; ++j) { l[j] = __expf(l[j] - m); s += l[j]; }
  float inv = 1.f / s;
  for (int j = 0; j < CH; ++j) AT[bh * (CH * CH) + j * CH + i] = l[j] * inv;
}

// ------------------------------------------------------------ out = attn . V
__global__ __launch_bounds__(256) void k_out(const float* __restrict__ AT,
                                             const unsigned short* __restrict__ Vp,
                                             void* __restrict__ Out,
                                             const unsigned short* __restrict__ x) {
  bool f32 = detect_f32(x);
  int bh = blockIdx.y, b = bh >> 2, h = bh & 3;
  int p0 = (blockIdx.x * 256 + threadIdx.x) * 2;
  const float* A = AT + bh * (CH * CH);            // [j][i], block-uniform
  const unsigned short* Vb = Vp + ((size_t)b * NC + h * CH) * NN;
  float a1[CH], a2[CH];
  for (int i = 0; i < CH; ++i) { a1[i] = 0.f; a2[i] = 0.f; }
  for (int j = 0; j < CH; ++j) {
    unsigned int u = *(const unsigned int*)(Vb + (size_t)j * NN + p0);
    float v1 = bf2f((unsigned short)(u & 0xFFFF));
    float v2 = bf2f((unsigned short)(u >> 16));
    const float* Aj = A + j * CH;
    for (int i = 0; i < CH; ++i) {
      float a = Aj[i];
      a1[i] += a * v1;
      a2[i] += a * v2;
    }
  }
  size_t obase = ((size_t)b * NC + h * CH) * NN;
  if (f32) {
    float* Of = (float*)Out;
    for (int i = 0; i < CH; ++i)
      *(float2*)(Of + obase + (size_t)i * NN + p0) = make_float2(a1[i], a2[i]);
  } else {
    unsigned short* Ob = (unsigned short*)Out;
    for (int i = 0; i < CH; ++i) {
      unsigned int u = ((unsigned int)f2bf(a2[i]) << 16) | f2bf(a1[i]);
      *(unsigned int*)(Ob + obase + (size_t)i * NN + p0) = u;
    }
  }
}

// ------------------------------------------------------------ launch
extern "C" void kernel_launch(void* const* d_in, const int* in_sizes, int n_in,
                              void* d_out, int out_size, void* d_ws, size_t ws_size,
                              hipStream_t stream) {
  const unsigned short* x = (const unsigned short*)d_in[0];

  const size_t TEN = (size_t)NB * NC * NN;   // 12,582,912 elems
  unsigned short* bufA = (unsigned short*)d_ws;   // Q'
  unsigned short* bufB = bufA + TEN;              // K'
  unsigned short* bufV = bufB + TEN;              // V'
  unsigned short* Xt   = bufV + TEN;              // X transposed (bf16)
  unsigned short* Yall = Xt + TEN;                // 3 conv outputs (75.5 MB)
  float* ssq = (float*)(Yall + 3 * TEN);
  float* ssk = ssq + NB * NC;
  float* S   = ssk + NB * NC;
  float* AT  = S + 16 * CH * CH;
  unsigned short* canon = (unsigned short*)(AT + 16 * CH * CH);
  // ws total ~= 176.6 MB (< 268 MB)
  const unsigned short* Wall = canon;             // Wq|Wk|Wv = 576x192
  const unsigned short* Wdall = canon + 110592;   // wqd|wkd|wvd = 576x9
  const unsigned short* Tmp = canon + 115776;

  k_pre<<<453 + (NZERO + 255) / 256, 256, 0, stream>>>(
      x, d_in[1], d_in[3], d_in[5], d_in[2], d_in[4], d_in[6], d_in[7], canon, ssq);
  k_transpose<<<dim3(NN / 64, NC / 64, NB), 256, 0, stream>>>(x, Xt);
  k_conv<<<dim3(NN / 128, NB), 256, 0, stream>>>(Wall, Xt, Yall);
  k_dwconv<<<dim3(4, 3 * NC, NB), 256, 0, stream>>>(Yall, Wdall, bufA, bufB, bufV, ssq, ssk);
  k_attn<<<dim3(16, 16), 256, 0, stream>>>(bufA, bufB, S);
  k_softmax<<<16, 64, 0, stream>>>(S, ssq, ssk, Tmp, AT);
  k_out<<<dim3(NN / 512, 16), 256, 0, stream>>>(AT, bufV, d_out, x);
}

// Round 7
// 240.221 us; speedup vs baseline: 1.3807x; 1.0563x over previous
//
#include <hip/hip_runtime.h>
#include <hip/hip_bf16.h>

// Restormer-style channel attention (MDTA). b=4, c=192, h=w=128 (n=16384),
// heads=4, ch=48. I/O fp32 (runtime-detected, bf16 tolerated).
//
// Launches:
//   k_pre:       weights -> canonical bf16, zero ssq/ssk/S
//   k_transpose: X[b][c][n] fp32 -> Xt[b][n][c] bf16 (64x64 tiles, pad 65)
//   k_conv:      fused q|k|v conv1x1 MFMA -> Yall[proj][b][c][n]
//   k_dwconv:    fused q|k|v depthwise 3x3 — LDS-free SLIDING WINDOW:
//                one block per (proj,b,c) image; thread = 8col x 8row strip;
//                each input row loaded ONCE (3 rotating register rows, halo
//                via __shfl); wave-reduced sumsq
//   k_attn:      S = Q.K^T (MFMA over n, 16 chunks, atomics)
//   k_softmax:   fold L2 norms + temperature (normalize commutes with dot)
//   k_out:       out = attn . V (K=48 skinny GEMM, fp32 out)

typedef __attribute__((ext_vector_type(8))) short short8;
typedef __attribute__((ext_vector_type(4))) float f32x4;

#define NB 4
#define NC 192
#define NN 16384
#define CH 48
#define NWELEM 115780     // 3*36864 + 3*1728 + 4
#define NZERO 38400       // ssq(768) + ssk(768) + S(16*48*48) floats

__device__ inline unsigned short f2bf(float f) {
  union { float f; unsigned int u; } c; c.f = f;
  unsigned int r = c.u + 0x7FFF + ((c.u >> 16) & 1);   // RNE
  return (unsigned short)(r >> 16);
}
__device__ inline float bf2f(unsigned short u) {
  union { unsigned int u; float f; } c; c.u = ((unsigned int)u) << 16;
  return c.f;
}

// fp32 (true) vs bf16 (false), wave-uniform.
__device__ inline bool detect_f32(const unsigned short* x) {
  int l = threadIdx.x & 63;
  unsigned short u = x[2 * (l * 997 + 1)];
  int e = (u >> 7) & 0xFF;
  bool extreme = (e < 90) || (e > 165);
  return __popcll(__ballot(extreme)) >= 8;
}

// ------------------------------------------------------------ pre: convert + zero
__global__ __launch_bounds__(256) void k_pre(const unsigned short* __restrict__ x,
                                             const void* wq, const void* wk, const void* wv,
                                             const void* wqd, const void* wkd, const void* wvd,
                                             const void* temp,
                                             unsigned short* __restrict__ canon,
                                             float* __restrict__ zbase) {
  int blk = blockIdx.x;
  if (blk >= 453) {   // zero range
    int i = (blk - 453) * 256 + threadIdx.x;
    if (i < NZERO) zbase[i] = 0.f;
    return;
  }
  bool f32 = detect_f32(x);
  int i = blk * 256 + threadIdx.x;
  if (i >= NWELEM) return;
  const void* src; int off;
  if (i < 36864)       { src = wq;  off = i; }
  else if (i < 73728)  { src = wk;  off = i - 36864; }
  else if (i < 110592) { src = wv;  off = i - 73728; }
  else if (i < 112320) { src = wqd; off = i - 110592; }
  else if (i < 114048) { src = wkd; off = i - 112320; }
  else if (i < 115776) { src = wvd; off = i - 114048; }
  else                 { src = temp; off = i - 115776; }
  canon[i] = f32 ? f2bf(((const float*)src)[off])
                 : ((const unsigned short*)src)[off];
}

// ------------------------------------------------------------ transpose+convert
__global__ __launch_bounds__(256) void k_transpose(const unsigned short* __restrict__ X,
                                                   unsigned short* __restrict__ Xt) {
  __shared__ unsigned short tile[64 * 65];
  bool f32 = detect_f32(X);
  int b = blockIdx.z, c0 = blockIdx.y * 64, p0 = blockIdx.x * 64;
  int tid = threadIdx.x;
  if (f32) {
    const float* Xf = (const float*)X;
    for (int it = 0; it < 16; ++it) {
      int idx = it * 256 + tid;
      int c = idx >> 6, p = idx & 63;
      tile[c * 65 + p] = f2bf(Xf[((size_t)b * NC + c0 + c) * NN + p0 + p]);
    }
  } else {
    for (int it = 0; it < 16; ++it) {
      int idx = it * 256 + tid;
      int c = idx >> 6, p = idx & 63;
      tile[c * 65 + p] = X[((size_t)b * NC + c0 + c) * NN + p0 + p];
    }
  }
  __syncthreads();
  for (int it = 0; it < 2; ++it) {
    int idx = it * 256 + tid;
    int cc = idx & 7, p = idx >> 3;
    short8 v;
#pragma unroll
    for (int j = 0; j < 8; ++j) v[j] = (short)tile[(cc * 8 + j) * 65 + p];
    *(short8*)(Xt + ((size_t)b * NN + p0 + p) * NC + c0 + cc * 8) = v;
  }
}

// ------------------------------------------------------------ fused conv1x1 (MFMA)
// Yall[proj][b][d][p] = sum_c Wall[proj*192+d][c] * Xt[b][p][c]
#define LDP 200
__global__ __launch_bounds__(256) void k_conv(const unsigned short* __restrict__ Wall,
                                              const unsigned short* __restrict__ Xt,
                                              unsigned short* __restrict__ Yall) {
  __shared__ __align__(16) unsigned short Xs[128 * LDP];  // 51.2 KB
  int b = blockIdx.y, p0 = blockIdx.x * 128;
  int tid = threadIdx.x;
  const unsigned short* tb = Xt + ((size_t)b * NN + p0) * NC;  // contiguous 48KB
  for (int it = 0; it < 12; ++it) {
    int idx = it * 256 + tid;
    short8 v = *(const short8*)(tb + idx * 8);
    int p = idx / 24, cc = idx % 24;
    *(short8*)(&Xs[p * LDP + cc * 8]) = v;
  }
  __syncthreads();
  int lane = tid & 63, w = tid >> 6;
  int wm = w & 1, wn = w >> 1;        // wave -> 32d x 64p quadrant
  int lrow = lane & 15, lq = lane >> 4;
  // preload this wave's B-frags for all 6 k-steps (reused 9x)
  short8 bf[6][4];
  for (int ks = 0; ks < 6; ++ks)
    for (int nt = 0; nt < 4; ++nt)
      bf[ks][nt] = *(const short8*)(&Xs[(wn * 64 + nt * 16 + lrow) * LDP + ks * 32 + lq * 8]);
  for (int dt = 0; dt < 9; ++dt) {    // 9 d-tiles of 64 over 576 rows
    int d0 = dt * 64;
    f32x4 acc[2][4];
    for (int mt = 0; mt < 2; ++mt)
      for (int nt = 0; nt < 4; ++nt) acc[mt][nt] = (f32x4){0.f, 0.f, 0.f, 0.f};
    for (int ks = 0; ks < 6; ++ks) {
      int k = ks * 32 + lq * 8;
      short8 a[2];
      for (int mt = 0; mt < 2; ++mt)
        a[mt] = *(const short8*)(Wall + (size_t)(d0 + wm * 32 + mt * 16 + lrow) * NC + k);
      for (int mt = 0; mt < 2; ++mt)
        for (int nt = 0; nt < 4; ++nt)
          acc[mt][nt] = __builtin_amdgcn_mfma_f32_16x16x32_bf16(a[mt], bf[ks][nt], acc[mt][nt], 0, 0, 0);
    }
    int proj = dt / 3, c0 = (dt % 3) * 64;
    unsigned short* Yb = Yall + (((size_t)proj * NB + b) * NC) * NN;
    for (int mt = 0; mt < 2; ++mt)
      for (int nt = 0; nt < 4; ++nt)
        for (int r = 0; r < 4; ++r) {
          int c = c0 + wm * 32 + mt * 16 + lq * 4 + r;
          int p = p0 + wn * 64 + nt * 16 + lrow;
          Yb[(size_t)c * NN + p] = f2bf(acc[mt][nt][r]);
        }
  }
}

// ------------------------------------------------------------ fused dwconv3x3 (+ sumsq)
// Sliding window, LDS-free. One block = one (proj,b,c) 128x128 image.
// Thread: 8-col chunk (ch) x 8-row group (rg). 3 rotating register rows,
// each input row loaded once; halo cols via __shfl.
__global__ __launch_bounds__(256) void k_dwconv(const unsigned short* __restrict__ Yall,
                                                const unsigned short* __restrict__ Wdall,
                                                unsigned short* __restrict__ Pq,
                                                unsigned short* __restrict__ Pk,
                                                unsigned short* __restrict__ Pv,
                                                float* __restrict__ ssq,
                                                float* __restrict__ ssk) {
  int y = blockIdx.x, b = blockIdx.y;
  int proj = y / NC, c = y % NC;
  int tid = threadIdx.x;
  int lane = tid & 63, ch = tid & 15, rg = tid >> 4;
  const unsigned short* base = Yall + (((size_t)proj * NB + b) * NC + c) * NN;
  unsigned short* P = (proj == 0 ? Pq : (proj == 1 ? Pk : Pv));
  float* ss = (proj == 0 ? ssq : (proj == 1 ? ssk : nullptr));
  float wk9[9];
#pragma unroll
  for (int i = 0; i < 9; ++i) wk9[i] = bf2f(Wdall[(proj * NC + c) * 9 + i]);
  int r0 = rg * 8;
  float rows[3][10];   // rows[i%3] holds extended input row (r0-1+i)

#define LOADROW(gy, dst)                                              \
  {                                                                   \
    float f0,f1,f2,f3,f4,f5,f6,f7;                                    \
    int _gy = (gy);                                                   \
    if (_gy >= 0 && _gy < 128) {                                      \
      short8 v = *(const short8*)(base + _gy * 128 + ch * 8);         \
      f0 = bf2f((unsigned short)v[0]); f1 = bf2f((unsigned short)v[1]); \
      f2 = bf2f((unsigned short)v[2]); f3 = bf2f((unsigned short)v[3]); \
      f4 = bf2f((unsigned short)v[4]); f5 = bf2f((unsigned short)v[5]); \
      f6 = bf2f((unsigned short)v[6]); f7 = bf2f((unsigned short)v[7]); \
    } else { f0=f1=f2=f3=f4=f5=f6=f7=0.f; }                           \
    float lf = __shfl(f7, lane - 1);                                  \
    float rf = __shfl(f0, lane + 1);                                  \
    if (ch == 0)  lf = 0.f;                                           \
    if (ch == 15) rf = 0.f;                                           \
    (dst)[0]=lf; (dst)[1]=f0; (dst)[2]=f1; (dst)[3]=f2; (dst)[4]=f3;  \
    (dst)[5]=f4; (dst)[6]=f5; (dst)[7]=f6; (dst)[8]=f7; (dst)[9]=rf;  \
  }

  LOADROW(r0 - 1, rows[0]);
  LOADROW(r0,     rows[1]);
  float ssacc = 0.f;
#pragma unroll
  for (int r = 0; r < 8; ++r) {
    LOADROW(r0 + r + 1, rows[(r + 2) % 3]);
    float z[8];
#pragma unroll
    for (int j = 0; j < 8; ++j) z[j] = 0.f;
#pragma unroll
    for (int dy = 0; dy < 3; ++dy) {
      const float* f = rows[(r + dy) % 3];
      float w0 = wk9[dy * 3], w1 = wk9[dy * 3 + 1], w2 = wk9[dy * 3 + 2];
#pragma unroll
      for (int j = 0; j < 8; ++j) z[j] += w0 * f[j] + w1 * f[j + 1] + w2 * f[j + 2];
    }
    short8 sv;
#pragma unroll
    for (int j = 0; j < 8; ++j) { sv[j] = (short)f2bf(z[j]); ssacc += z[j] * z[j]; }
    *(short8*)(P + ((size_t)b * NC + c) * NN + (r0 + r) * 128 + ch * 8) = sv;
  }
#undef LOADROW
  if (ss) {
    for (int off = 32; off; off >>= 1) ssacc += __shfl_down(ssacc, off);
    if (lane == 0) atomicAdd(&ss[b * NC + c], ssacc);
  }
}

// ------------------------------------------------------------ S = Q.K^T
__global__ __launch_bounds__(256) void k_attn(const unsigned short* __restrict__ Qp,
                                              const unsigned short* __restrict__ Kp,
                                              float* __restrict__ S) {
  __shared__ float Sred[CH * CH];
  int bh = blockIdx.y, chunk = blockIdx.x;
  int b = bh >> 2, h = bh & 3;
  int tid = threadIdx.x, lane = tid & 63, w = tid >> 6;
  int lrow = lane & 15, lq = lane >> 4;
  const unsigned short* Qb = Qp + ((size_t)b * NC + h * CH) * NN;
  const unsigned short* Kb = Kp + ((size_t)b * NC + h * CH) * NN;
  int nbase = chunk * 1024 + w * 256;
  f32x4 acc[3][3];
  for (int i = 0; i < 3; ++i)
    for (int j = 0; j < 3; ++j) acc[i][j] = (f32x4){0.f, 0.f, 0.f, 0.f};
  for (int ks = 0; ks < 8; ++ks) {
    int n = nbase + ks * 32 + lq * 8;
    short8 a[3], bb[3];
    for (int t = 0; t < 3; ++t) a[t]  = *(const short8*)(Qb + (size_t)(t * 16 + lrow) * NN + n);
    for (int t = 0; t < 3; ++t) bb[t] = *(const short8*)(Kb + (size_t)(t * 16 + lrow) * NN + n);
    for (int ti = 0; ti < 3; ++ti)
      for (int tj = 0; tj < 3; ++tj)
        acc[ti][tj] = __builtin_amdgcn_mfma_f32_16x16x32_bf16(a[ti], bb[tj], acc[ti][tj], 0, 0, 0);
  }
  for (int i = tid; i < CH * CH; i += 256) Sred[i] = 0.f;
  __syncthreads();
  for (int ti = 0; ti < 3; ++ti)
    for (int tj = 0; tj < 3; ++tj)
      for (int r = 0; r < 4; ++r) {
        int row = ti * 16 + lq * 4 + r, col = tj * 16 + lrow;
        atomicAdd(&Sred[row * CH + col], acc[ti][tj][r]);
      }
  __syncthreads();
  float* Sg = S + bh * (CH * CH);
  for (int i = tid; i < CH * CH; i += 256) atomicAdd(&Sg[i], Sred[i]);
}

// ------------------------------------------------------------ softmax (+ norms)
__global__ void k_softmax(const float* __restrict__ S, const float* __restrict__ ssq,
                          const float* __restrict__ ssk, const unsigned short* __restrict__ tempc,
                          float* __restrict__ AT) {   // AT[bh][j][i]
  int bh = blockIdx.x, b = bh >> 2, h = bh & 3;
  int i = threadIdx.x;
  if (i >= CH) return;
  float t = bf2f(tempc[h]);
  float rq = 1.f / fmaxf(sqrtf(ssq[b * NC + h * CH + i]), 1e-12f);
  const float* Srow = S + bh * (CH * CH) + i * CH;
  float l[CH];
  float m = -1e30f;
  for (int j = 0; j < CH; ++j) {
    float rk = 1.f / fmaxf(sqrtf(ssk[b * NC + h * CH + j]), 1e-12f);
    l[j] = Srow[j] * rq * rk * t;
    m = fmaxf(m, l[j]);
  }
  float s = 0.f;
  for (int j = 0; j < CH; ++j) { l[j] = __expf(l[j] - m); s += l[j]; }
  float inv = 1.f / s;
  for (int j = 0; j < CH; ++j) AT[bh * (CH * CH) + j * CH + i] = l[j] * inv;
}

// ------------------------------------------------------------ out = attn . V
__global__ __launch_bounds__(256) void k_out(const float* __restrict__ AT,
                                             const unsigned short* __restrict__ Vp,
                                             void* __restrict__ Out,
                                             const unsigned short* __restrict__ x) {
  bool f32 = detect_f32(x);
  int bh = blockIdx.y, b = bh >> 2, h = bh & 3;
  int p0 = (blockIdx.x * 256 + threadIdx.x) * 2;
  const float* A = AT + bh * (CH * CH);            // [j][i], block-uniform
  const unsigned short* Vb = Vp + ((size_t)b * NC + h * CH) * NN;
  float a1[CH], a2[CH];
  for (int i = 0; i < CH; ++i) { a1[i] = 0.f; a2[i] = 0.f; }
  for (int j = 0; j < CH; ++j) {
    unsigned int u = *(const unsigned int*)(Vb + (size_t)j * NN + p0);
    float v1 = bf2f((unsigned short)(u & 0xFFFF));
    float v2 = bf2f((unsigned short)(u >> 16));
    const float* Aj = A + j * CH;
    for (int i = 0; i < CH; ++i) {
      float a = Aj[i];
      a1[i] += a * v1;
      a2[i] += a * v2;
    }
  }
  size_t obase = ((size_t)b * NC + h * CH) * NN;
  if (f32) {
    float* Of = (float*)Out;
    for (int i = 0; i < CH; ++i)
      *(float2*)(Of + obase + (size_t)i * NN + p0) = make_float2(a1[i], a2[i]);
  } else {
    unsigned short* Ob = (unsigned short*)Out;
    for (int i = 0; i < CH; ++i) {
      unsigned int u = ((unsigned int)f2bf(a2[i]) << 16) | f2bf(a1[i]);
      *(unsigned int*)(Ob + obase + (size_t)i * NN + p0) = u;
    }
  }
}

// ------------------------------------------------------------ launch
extern "C" void kernel_launch(void* const* d_in, const int* in_sizes, int n_in,
                              void* d_out, int out_size, void* d_ws, size_t ws_size,
                              hipStream_t stream) {
  const unsigned short* x = (const unsigned short*)d_in[0];

  const size_t TEN = (size_t)NB * NC * NN;   // 12,582,912 elems
  unsigned short* bufA = (unsigned short*)d_ws;   // Q'
  unsigned short* bufB = bufA + TEN;              // K'
  unsigned short* bufV = bufB + TEN;              // V'
  unsigned short* Xt   = bufV + TEN;              // X transposed (bf16)
  unsigned short* Yall = Xt + TEN;                // 3 conv outputs (75.5 MB)
  float* ssq = (float*)(Yall + 3 * TEN);
  float* ssk = ssq + NB * NC;
  float* S   = ssk + NB * NC;
  float* AT  = S + 16 * CH * CH;
  unsigned short* canon = (unsigned short*)(AT + 16 * CH * CH);
  // ws total ~= 176.6 MB (< 268 MB)
  const unsigned short* Wall = canon;             // Wq|Wk|Wv = 576x192
  const unsigned short* Wdall = canon + 110592;   // wqd|wkd|wvd = 576x9
  const unsigned short* Tmp = canon + 115776;

  k_pre<<<453 + (NZERO + 255) / 256, 256, 0, stream>>>(
      x, d_in[1], d_in[3], d_in[5], d_in[2], d_in[4], d_in[6], d_in[7], canon, ssq);
  k_transpose<<<dim3(NN / 64, NC / 64, NB), 256, 0, stream>>>(x, Xt);
  k_conv<<<dim3(NN / 128, NB), 256, 0, stream>>>(Wall, Xt, Yall);
  k_dwconv<<<dim3(3 * NC, NB), 256, 0, stream>>>(Yall, Wdall, bufA, bufB, bufV, ssq, ssk);
  k_attn<<<dim3(16, 16), 256, 0, stream>>>(bufA, bufB, S);
  k_softmax<<<16, 64, 0, stream>>>(S, ssq, ssk, Tmp, AT);
  k_out<<<dim3(NN / 512, 16), 256, 0, stream>>>(AT, bufV, d_out, x);
}